// Round 11
// baseline (175.088 us; speedup 1.0000x reference)
//
#include <hip/hip_runtime.h>
#include <hip/hip_bf16.h>
#include <math.h>

#define Hn 6
#define Bn 512
#define Dn 2048
#define Cn 1000
#define Cpad 1024
#define TAUv 0.5f
#define NITF 64              // full-K iters per block (BK=32, KSPLIT=1)
#define NKT (Dn / 32)        // 64 ktiles total

typedef unsigned int u32;
typedef unsigned short u16;
typedef __attribute__((ext_vector_type(8))) short short8;
typedef __attribute__((ext_vector_type(4))) float f32x4;

union FragU { u32 d[4]; short8 s; };

// pack two fp32 -> one dword of bf16 (RNE, f0 in low half; lowers to v_cvt_pk_bf16_f32)
__device__ __forceinline__ u32 cvt_pk2(float f0, float f1) {
  union { __hip_bfloat162 h; u32 u; } cv;
  cv.h = __float22bfloat162_rn(make_float2(f0, f1));
  return cv.u;
}

// 8 fp32 -> hi/lo 16B chunks (RNE both; bit-identical to the 0.03125 pipeline)
__device__ __forceinline__ void pack8(const float* rr, uint4& hv, uint4& lv) {
  u32 hd[4], ld[4];
  float r[8];
#pragma unroll
  for (int i = 0; i < 4; ++i) {
    const u32 d = cvt_pk2(rr[2 * i], rr[2 * i + 1]);
    hd[i] = d;
    r[2 * i]     = rr[2 * i]     - __uint_as_float(d << 16);
    r[2 * i + 1] = rr[2 * i + 1] - __uint_as_float(d & 0xffff0000u);
  }
#pragma unroll
  for (int i = 0; i < 4; ++i) ld[i] = cvt_pk2(r[2 * i], r[2 * i + 1]);
  hv = make_uint4(hd[0], hd[1], hd[2], hd[3]);
  lv = make_uint4(ld[0], ld[1], ld[2], ld[3]);
}

// async global->LDS DMA, 16 B/lane; LDS dest = wave-uniform base + lane*16 (linear!)
__device__ __forceinline__ void dma16(const void* g, void* l) {
  __builtin_amdgcn_global_load_lds(
      (const __attribute__((address_space(1))) u32*)g,
      (__attribute__((address_space(3))) u32*)l, 16, 0, 0);
}

// ============ conv_k (proven): fp32 -> k-tiled split-bf16 ============
// yy < 4 : feats [H][B][D] -> Ah/Al [H][64][4][512][8]
// yy >= 4: W [H][D][C] -> transposed Bh/Bl [H][64][4][1024][8] (zeros past Cn)
__global__ __launch_bounds__(256) void conv_k(
    const float* __restrict__ feats, const float* __restrict__ W,
    u16* __restrict__ Ah, u16* __restrict__ Al,
    u16* __restrict__ Bh, u16* __restrict__ Bl, u32* __restrict__ ticket)
{
  __shared__ float smem[128 * 33];   // aconv: [128][33]; bconv: [32][129]
  const int t   = blockIdx.x;        // ktile 0..63
  const int yy  = blockIdx.y;        // 0..11
  const int h   = blockIdx.z;
  const int tid = threadIdx.x;

  if (t == 0 && yy == 0 && h == 0 && tid == 0) *ticket = 0;   // for confpick's gate

  if (yy < 4) {
    const int r0 = yy * 128;
#pragma unroll
    for (int i = 0; i < 4; ++i) {
      const int f = i * 256 + tid;     // 0..1023 float4 tasks
      const int r = f >> 3, q = f & 7;
      const float4 v = *(const float4*)(feats + ((size_t)(h * Bn + r0 + r) * Dn + t * 32 + q * 4));
      smem[r * 33 + q * 4 + 0] = v.x; smem[r * 33 + q * 4 + 1] = v.y;
      smem[r * 33 + q * 4 + 2] = v.z; smem[r * 33 + q * 4 + 3] = v.w;
    }
    __syncthreads();
#pragma unroll
    for (int i = 0; i < 2; ++i) {
      const int j = i * 256 + tid;     // 0..511 chunk tasks
      const int c = j >> 7, r = j & 127;
      float rr[8];
#pragma unroll
      for (int e = 0; e < 8; ++e) rr[e] = smem[r * 33 + c * 8 + e];
      uint4 hv, lv;
      pack8(rr, hv, lv);
      const size_t o = (((size_t)(h * 64 + t) * 4 + c) * 512 + r0 + r);
      ((uint4*)Ah)[o] = hv;
      ((uint4*)Al)[o] = lv;
    }
  } else {
    const int n0 = (yy - 4) * 128;
#pragma unroll
    for (int i = 0; i < 4; ++i) {
      const int f = i * 256 + tid;     // 0..1023
      const int k = f >> 5, q = f & 31;
      const int n = n0 + q * 4;
      const float* src = W + ((size_t)h * Dn + t * 32 + k) * Cn;
      float4 v = make_float4(0.f, 0.f, 0.f, 0.f);
      if (n + 3 < Cn) {
        v = *(const float4*)(src + n);
      } else {
        if (n + 0 < Cn) v.x = src[n + 0];
        if (n + 1 < Cn) v.y = src[n + 1];
        if (n + 2 < Cn) v.z = src[n + 2];
        if (n + 3 < Cn) v.w = src[n + 3];
      }
      smem[k * 129 + q * 4 + 0] = v.x; smem[k * 129 + q * 4 + 1] = v.y;
      smem[k * 129 + q * 4 + 2] = v.z; smem[k * 129 + q * 4 + 3] = v.w;
    }
    __syncthreads();
#pragma unroll
    for (int i = 0; i < 2; ++i) {
      const int j = i * 256 + tid;     // 0..511
      const int c = j >> 7, n = j & 127;
      float rr[8];
#pragma unroll
      for (int e = 0; e < 8; ++e) rr[e] = smem[(c * 8 + e) * 129 + n];
      uint4 hv, lv;
      pack8(rr, hv, lv);
      const size_t o = (((size_t)(h * 64 + t) * 4 + c) * 1024 + n0 + n);
      ((uint4*)Bh)[o] = hv;
      ((uint4*)Bl)[o] = lv;
    }
  }
}

// ============ split-bf16 MFMA GEMM: prepacked, 3-buffer 2-deep pipeline ============
// Tile 64(M)x64(N), BK=32, KSPLIT=1 (full K per block). LDS 3 x 16 KB = 48 KB
// -> 3 blocks/CU; grid 768 = 16n x 8m x 6h = 256 CU x 3 resident, perfect balance.
// T4 2-deep: tiles it+1, it+2 in flight (8 dma) while computing tile it; uniform
// 4 dma/wave/tile -> wave-uniform vmcnt(8). Wave w stages matrix w (1KB bursts).
// Frag reads: same proven zero-conflict pattern as R9/R10 (2-way b128 = free).
__global__ __launch_bounds__(256, 3) void gemm_k(
    const u16* __restrict__ AhG, const u16* __restrict__ AlG,
    const u16* __restrict__ BhG, const u16* __restrict__ BlG,
    const float* __restrict__ bias, float* __restrict__ logits)
{
  const int bid = blockIdx.x;
  const int wg = (bid & 7) * 96 + (bid >> 3);   // XCD-chunked: 96 consecutive per XCD
  const int n0 = (wg & 15) * 64;
  const int m0 = ((wg >> 4) & 7) * 64;
  const int h  = wg >> 7;                        // 0..5
  const int t = threadIdx.x, lane = t & 63, w = t >> 6;

  __shared__ __align__(16) char lds[3][16384];   // per buf: Ah 4K | Al 4K | Bh 4K | Bl 4K

  // wave w stages matrix w; k-tiled layout -> each dma16 is a 1KB coalesced burst
  const u16* gmat = (w == 0) ? AhG : (w == 1) ? AlG : (w == 2) ? BhG : BlG;
  const int  R    = (w < 2) ? 512 : 1024;
  const int  row0 = (w < 2) ? m0 : n0;
  const uint4* g0 = (const uint4*)gmat + ((size_t)(h * 64) * 4) * R + row0 + lane;
  const int dstw = w * 4096 + lane * 16;

  const int fl = lane & 15, fq = lane >> 4;
  const int wm = (w & 1) * 32, wn = (w >> 1) * 32;

  f32x4 acc[2][2];
#pragma unroll
  for (int i = 0; i < 2; ++i)
#pragma unroll
    for (int j = 0; j < 2; ++j) acc[i][j] = (f32x4){0.f, 0.f, 0.f, 0.f};

#define STAGE(TILE, BUF)                                                              \
  {                                                                                   \
    char* sb = &lds[BUF][0];                                                          \
    const uint4* g = g0 + (size_t)(TILE) * 4 * R;                                     \
    _Pragma("unroll")                                                                 \
    for (int c = 0; c < 4; ++c)                                                       \
      dma16(g + (size_t)c * R, sb + dstw + c * 1024);                                 \
  }

#define COMPUTE_TILE(BUF)                                                             \
  {                                                                                   \
    const char* bb = &lds[BUF][0];                                                    \
    FragU ah[2], al[2];                                                               \
    _Pragma("unroll")                                                                 \
    for (int mt = 0; mt < 2; ++mt) {                                                  \
      const int r = wm + mt * 16 + fl;                                                \
      ah[mt].s = *(const short8*)(bb + (fq * 64 + r) * 16);                           \
      al[mt].s = *(const short8*)(bb + 4096 + (fq * 64 + r) * 16);                    \
    }                                                                                 \
    _Pragma("unroll")                                                                 \
    for (int nt = 0; nt < 2; ++nt) {                                                  \
      const int n = wn + nt * 16 + fl;                                                \
      FragU bh, bl;                                                                   \
      bh.s = *(const short8*)(bb + 8192  + (fq * 64 + n) * 16);                       \
      bl.s = *(const short8*)(bb + 12288 + (fq * 64 + n) * 16);                       \
      _Pragma("unroll")                                                               \
      for (int mt = 0; mt < 2; ++mt) {                                                \
        acc[mt][nt] = __builtin_amdgcn_mfma_f32_16x16x32_bf16(ah[mt].s, bh.s, acc[mt][nt], 0, 0, 0); \
        acc[mt][nt] = __builtin_amdgcn_mfma_f32_16x16x32_bf16(ah[mt].s, bl.s, acc[mt][nt], 0, 0, 0); \
        acc[mt][nt] = __builtin_amdgcn_mfma_f32_16x16x32_bf16(al[mt].s, bh.s, acc[mt][nt], 0, 0, 0); \
      }                                                                               \
    }                                                                                 \
  }

  // prologue: 2 tiles in flight before first compute
  STAGE(0, 0);
  STAGE(1, 1);

  int bc = 0;                                     // buffer holding tile 'it'
  for (int it = 0; it < NITF; ++it) {
    if (it + 2 < NITF) {
      const int pb = (bc + 2 >= 3) ? (bc - 1) : (bc + 2);
      STAGE(it + 2, pb);                          // keep 2 tiles ahead in flight
    }
    if (it < NITF - 2)
      asm volatile("s_waitcnt vmcnt(8)" ::: "memory");   // tile it landed; it+1,it+2 fly
    else if (it == NITF - 2)
      asm volatile("s_waitcnt vmcnt(4)" ::: "memory");
    else
      asm volatile("s_waitcnt vmcnt(0)" ::: "memory");
    __builtin_amdgcn_s_barrier();
    __builtin_amdgcn_sched_barrier(0);
    __builtin_amdgcn_s_setprio(1);
    COMPUTE_TILE(bc);
    __builtin_amdgcn_s_setprio(0);
    __builtin_amdgcn_sched_barrier(0);
    asm volatile("s_waitcnt lgkmcnt(0)" ::: "memory");   // reads of buf bc done
    __builtin_amdgcn_s_barrier();                 // safe: buf bc overwritten at it+1's STAGE
    bc = (bc + 1 >= 3) ? 0 : bc + 1;
  }
#undef COMPUTE_TILE
#undef STAGE

  // ---- stores (+bias; KSPLIT=1 -> final logits directly), proven mapping ----
#pragma unroll
  for (int nt = 0; nt < 2; ++nt) {
    const int col = n0 + wn + nt * 16 + fl;
    if (col >= Cn) continue;
    const float bv = bias[(size_t)h * Cn + col];
#pragma unroll
    for (int mt = 0; mt < 2; ++mt) {
      const int rbase = m0 + wm + mt * 16 + fq * 4;
#pragma unroll
      for (int r = 0; r < 4; ++r)
        logits[((size_t)h * Bn + rbase + r) * Cn + col] = acc[mt][nt][r] + bv;
    }
  }
}

// ============ fused conf + route + gather + CE; last block reduces scalars ============
__global__ __launch_bounds__(256) void confpick_k(
    const float* __restrict__ logits, const int* __restrict__ y,
    float* __restrict__ out, float* __restrict__ out_exit,
    float* __restrict__ loss_b, float* __restrict__ corr_b,
    u32* __restrict__ ticket, float* __restrict__ scalars)
{
  const int b = blockIdx.x, tid = threadIdx.x;
  const int lane = tid & 63, w = tid >> 6;
  __shared__ float ms[Hn], ss[Hn];

  // ---- per-row softmax stats: wave w covers rows w and w+4 ----
  for (int h = w; h < Hn; h += 4) {
    const float* p = logits + ((size_t)h * Bn + b) * Cn;
    float vv[16];
#pragma unroll
    for (int i = 0; i < 4; ++i) {
      const int c4 = i * 256 + lane * 4;
      if (c4 + 3 < Cn) {
        const float4 v0 = *(const float4*)(p + c4);
        vv[4 * i + 0] = v0.x; vv[4 * i + 1] = v0.y;
        vv[4 * i + 2] = v0.z; vv[4 * i + 3] = v0.w;
      } else {
#pragma unroll
        for (int j = 0; j < 4; ++j) {
          const int c = c4 + j;
          vv[4 * i + j] = (c < Cn) ? p[c] : -3.4e38f;
        }
      }
    }
    float m = -3.4e38f;
#pragma unroll
    for (int i = 0; i < 16; ++i) m = fmaxf(m, vv[i]);
#pragma unroll
    for (int off = 32; off >= 1; off >>= 1) m = fmaxf(m, __shfl_xor(m, off));
    float s = 0.f;
#pragma unroll
    for (int i = 0; i < 16; ++i) s += (vv[i] > -3.0e38f) ? expf(vv[i] - m) : 0.f;
#pragma unroll
    for (int off = 32; off >= 1; off >>= 1) s += __shfl_xor(s, off);
    if (lane == 0) { ms[h] = m; ss[h] = s; }
  }
  __syncthreads();

  // ---- route (uniform across block, from LDS stats) ----
  int first = -1, best = 0;
  float bestc = -3.4e38f;
#pragma unroll
  for (int h = 0; h < Hn; ++h) {
    const float c = 1.0f / ss[h];                   // max softmax prob
    if (first < 0 && c >= TAUv) first = h;
    if (c > bestc) { bestc = c; best = h; }         // strict > keeps first occurrence
  }
  const int ex = (first >= 0) ? first : best;
  const float* p = logits + ((size_t)ex * Bn + b) * Cn;

  // ---- gather chosen row (cache-warm re-read), argmax, store ----
  const int c4 = tid * 4;
  float vv[4] = {-3.4e38f, -3.4e38f, -3.4e38f, -3.4e38f};
  if (c4 + 3 < Cn) {
    const float4 v0 = *(const float4*)(p + c4);
    vv[0] = v0.x; vv[1] = v0.y; vv[2] = v0.z; vv[3] = v0.w;
  }
  float vm = -3.4e38f; int im = 1 << 30;
#pragma unroll
  for (int j = 0; j < 4; ++j) {
    const int c = c4 + j;
    if (c < Cn) {
      out[(size_t)b * Cn + c] = vv[j];
      if (vv[j] > vm) { vm = vv[j]; im = c; }       // ascending c keeps first max
    }
  }
#pragma unroll
  for (int off = 32; off >= 1; off >>= 1) {
    const float ov = __shfl_xor(vm, off);
    const int   oi = __shfl_xor(im, off);
    if (ov > vm || (ov == vm && oi < im)) { vm = ov; im = oi; }
  }
  __shared__ float rm[4]; __shared__ int ri[4];
  __shared__ u32 tk;
  if (lane == 0) { rm[w] = vm; ri[w] = im; }
  __syncthreads();
  if (tid == 0) {
    float bm = rm[0]; int bi = ri[0];
    for (int q = 1; q < 4; ++q)
      if (rm[q] > bm || (rm[q] == bm && ri[q] < bi)) { bm = rm[q]; bi = ri[q]; }
    const int yt = y[b];
    const float lp = p[yt] - ms[ex] - logf(ss[ex]);
    out_exit[b] = (float)ex;
    loss_b[b] = -lp;
    corr_b[b] = (bi == yt) ? 1.f : 0.f;
    __threadfence();                    // release: stores visible before ticket inc
    tk = atomicAdd(ticket, 1u);
  }
  __syncthreads();

  // ---- last arriving block reduces 512 -> 2 scalars (deterministic tree) ----
  if (tk == (u32)(Bn - 1)) {
    __threadfence();                    // acquire: see all other blocks' stores
    float l = loss_b[tid] + loss_b[tid + 256];
    float c = corr_b[tid] + corr_b[tid + 256];
#pragma unroll
    for (int off = 32; off >= 1; off >>= 1) {
      l += __shfl_xor(l, off);
      c += __shfl_xor(c, off);
    }
    __shared__ float sl[4], sc[4];
    if (lane == 0) { sl[w] = l; sc[w] = c; }
    __syncthreads();
    if (tid == 0) {
      scalars[0] = (sl[0] + sl[1] + sl[2] + sl[3]) * (1.0f / (float)Bn);
      scalars[1] = (sc[0] + sc[1] + sc[2] + sc[3]) * (1.0f / (float)Bn);
    }
  }
}

extern "C" void kernel_launch(void* const* d_in, const int* in_sizes, int n_in,
                              void* d_out, int out_size, void* d_ws, size_t ws_size,
                              hipStream_t stream) {
  const float* feats = (const float*)d_in[0];   // [H,B,D] fp32
  const float* W     = (const float*)d_in[1];   // [H,D,C] fp32
  const float* bias  = (const float*)d_in[2];   // [H,C]
  const int*   y     = (const int*)d_in[3];     // [B]
  float* out = (float*)d_out;                   // [B*C | B | 1 | 1]

  // ws: logits (12,288,000 B) + loss/corr/ticket + Ah/Al (12.6 MB ea) + Bh/Bl (25.2 MB ea)
  float* logits = (float*)d_ws;
  float* loss_b = logits + (size_t)Hn * Bn * Cn;
  float* corr_b = loss_b + Bn;
  u32*   ticket = (u32*)(corr_b + Bn);
  u16*   AhG    = (u16*)(ticket + 64);          // pad to 16B+ alignment
  u16*   AlG    = AhG + (size_t)Hn * NKT * 4 * 512 * 8;
  u16*   BhG    = AlG + (size_t)Hn * NKT * 4 * 512 * 8;
  u16*   BlG    = BhG + (size_t)Hn * NKT * 4 * 1024 * 8;
  float* out_exit    = out + (size_t)Bn * Cn;
  float* out_scalars = out + (size_t)Bn * Cn + Bn;

  conv_k<<<dim3(NKT, 12, Hn), 256, 0, stream>>>(feats, W, AhG, AlG, BhG, BlG, ticket);
  gemm_k<<<dim3(768, 1, 1), 256, 0, stream>>>(AhG, AlG, BhG, BlG, bias, logits);
  confpick_k<<<Bn, 256, 0, stream>>>(logits, y, out, out_exit, loss_b, corr_b,
                                     ticket, out_scalars);
}